// Round 2
// baseline (4893.438 us; speedup 1.0000x reference)
//
#include <hip/hip_runtime.h>

#define Bq   16
#define Nseq 1024
#define Cdim 768
#define NH2  24
#define HD   64
#define W2D  1536
#define KB   16
#define NMB  64

__device__ __forceinline__ float lane_bcast(float v, int lane) {
  return __int_as_float(__builtin_amdgcn_readlane(__float_as_int(v), lane));
}

// ---------------- generic f32 tiled GEMM: C[M,N] = A[M,K] @ B[K,N] (+bias) ---
__global__ __launch_bounds__(256) void gemm_f32_kernel(
    const float* __restrict__ A, const float* __restrict__ B,
    const float* __restrict__ bias, float* __restrict__ C,
    int M, int Kd, int Nd)
{
  __shared__ float As[64 * 17];   // [m][kk], padded
  __shared__ float Bs[16 * 65];   // [kk][n], padded
  const int t = threadIdx.x;
  const int tx = t & 15, ty = t >> 4;
  const int bx = blockIdx.x * 64, by = blockIdx.y * 64;
  float acc[4][4] = {};
  for (int k0 = 0; k0 < Kd; k0 += 16) {
#pragma unroll
    for (int r = 0; r < 4; ++r) {
      int q = t + 256 * r;
      int m = q >> 4, kk = q & 15;
      As[m * 17 + kk] = A[(size_t)(by + m) * Kd + k0 + kk];
    }
#pragma unroll
    for (int r = 0; r < 4; ++r) {
      int q = t + 256 * r;
      int kk = q >> 6, n = q & 63;
      Bs[kk * 65 + n] = B[(size_t)(k0 + kk) * Nd + bx + n];
    }
    __syncthreads();
#pragma unroll
    for (int kk = 0; kk < 16; ++kk) {
      float av[4], bv[4];
#pragma unroll
      for (int i2 = 0; i2 < 4; ++i2) av[i2] = As[(ty * 4 + i2) * 17 + kk];
#pragma unroll
      for (int j2 = 0; j2 < 4; ++j2) bv[j2] = Bs[kk * 65 + tx * 4 + j2];
#pragma unroll
      for (int i2 = 0; i2 < 4; ++i2)
#pragma unroll
        for (int j2 = 0; j2 < 4; ++j2)
          acc[i2][j2] += av[i2] * bv[j2];
    }
    __syncthreads();
  }
#pragma unroll
  for (int i2 = 0; i2 < 4; ++i2) {
    int row = by + ty * 4 + i2;
#pragma unroll
    for (int j2 = 0; j2 < 4; ++j2) {
      int col = bx + tx * 4 + j2;
      float v = acc[i2][j2];
      if (bias) v += bias[col];
      C[(size_t)row * Nd + col] = v;
    }
  }
}

// ---------------- lr = sigmoid(xx @ lr_w + lr_b) / hd ------------------------
__global__ __launch_bounds__(256) void lr_kernel(
    const float* __restrict__ x, const float* __restrict__ lr_w,
    const float* __restrict__ lr_b, float* __restrict__ lrout)
{
  int idx = blockIdx.x * 256 + threadIdx.x;
  if (idx >= Bq * Nseq * NH2) return;
  int hh = idx % NH2;
  int row = idx / NH2;
  int b = row >> 10, n = row & 1023;
  const float* x1 = x + (size_t)row * Cdim;
  const float* x2 = x + (size_t)(b * Nseq + (Nseq - 1 - n)) * Cdim;
  float acc = lr_b[hh];
  for (int c = 0; c < Cdim; ++c) acc += x1[c] * lr_w[c * NH2 + hh];
  for (int c = 0; c < Cdim; ++c) acc += x2[c] * lr_w[(Cdim + c) * NH2 + hh];
  float sg = 1.f / (1.f + expf(-acc));
  lrout[idx] = sg * (1.f / 64.f);
}

// ---------------- register-resident TTT scan: one WAVE per (b,h) chain -------
// lane l = output channel. Wr[c] = W[c][l]. No LDS, no barriers.
// Prefix trick: G_i[c][l] = sum_{j<=i} lr_j * xk[j][c] * grad[j][l]
//   -> masked-attn correction row i = sum_c xq[i][c] * G_i[c][l]
//   -> W update = tok15 * G_15  (free),  b update = tok15 * g0_15 (free)
__global__ __launch_bounds__(64, 1) void ttt_scan_reg_kernel(
    const float* __restrict__ qkv,   // (B,N,2304)
    const float* __restrict__ lrg,   // (B,N,24)
    const float* __restrict__ W1,    // (24,64,64)
    const float* __restrict__ b1g,   // (24,64)
    const float* __restrict__ lnw,   // (24,64)
    const float* __restrict__ lnb,   // (24,64)
    const float* __restrict__ tid,   // (16,)
    float* __restrict__ Zout)        // (B,N,1536)
{
  const int l = threadIdx.x;           // 0..63
  const int bh = blockIdx.x;
  const int b = bh / NH2, h = bh % NH2;
  const int chan = (h < 12) ? h * 64 : (h - 12) * 64;
  const bool flip = (h >= 12);

  float Wr[64];
#pragma unroll
  for (int c = 0; c < 64; ++c) Wr[c] = W1[h * 4096 + c * 64 + l];
  float breg = b1g[h * 64 + l];
  float gvr  = lnw[h * 64 + l];
  float btr  = lnb[h * 64 + l];

  float tokr[16];
#pragma unroll
  for (int i = 0; i < 16; ++i) {
    float tk = 1.f / (float)(i + 1) + tid[i];
    tokr[i] = tk > 0.f ? tk : 0.f;
  }
  // rotary tables: pair index p = l>>1, pos within minibatch = i
  float cr[16], sr[16];
  {
    float inv = expf(-((float)(2 * (l >> 1)) * (1.f / 64.f)) * 9.210340371976184f);
#pragma unroll
    for (int i = 0; i < 16; ++i) { cr[i] = cosf((float)i * inv); sr[i] = sinf((float)i * inv); }
  }
  const float sgn = (l & 1) ? 1.f : -1.f;

#pragma unroll 1
  for (int m = 0; m < NMB; ++m) {
    const int n0 = m * KB;
    // lr for the 16 rows of this minibatch (lane i holds row i, replicated x4)
    float lrl = lrg[((size_t)b * Nseq + n0 + (l & 15)) * NH2 + h];

    // ---- load q/k/v tile + rotary (lane = channel) ----
    float qr[16], kr[16], vr[16];
#pragma unroll
    for (int i = 0; i < 16; ++i) {
      int n = n0 + i;
      int grow = b * Nseq + (flip ? (Nseq - 1 - n) : n);
      const float* base = qkv + (size_t)grow * 2304 + chan + l;
      float qv = base[0], kv = base[768], vv = base[1536];
      float qo = __shfl_xor(qv, 1), ko = __shfl_xor(kv, 1);
      qr[i] = qv * cr[i] + qo * sr[i] * sgn;
      kr[i] = kv * cr[i] + ko * sr[i] * sgn;
      vr[i] = vv;
    }

    // ---- pass 1: z1_i = xk_i @ W + b  ->  grad_i (LN-L2 backward) ----
    float gr[16];
#pragma unroll
    for (int i = 0; i < 16; ++i) {
      float acc = 0.f;
#pragma unroll
      for (int c = 0; c < 64; ++c) acc += lane_bcast(kr[i], c) * Wr[c];
      float z = acc + breg;
      float s1 = z, s2 = z * z;
#pragma unroll
      for (int o = 1; o < 64; o <<= 1) { s1 += __shfl_xor(s1, o); s2 += __shfl_xor(s2, o); }
      float mu = s1 * 0.015625f;
      float var = s2 * 0.015625f - mu * mu;
      float rstd = rsqrtf(var + 1e-6f);
      float xh = (z - mu) * rstd;
      float gout = gvr * xh + btr - (vr[i] - kr[i]);
      float gxh = gout * gvr;
      float r1 = gxh, r2 = gxh * xh;
#pragma unroll
      for (int o = 1; o < 64; o <<= 1) { r1 += __shfl_xor(r1, o); r2 += __shfl_xor(r2, o); }
      gr[i] = (64.f * gxh - r1 - xh * r2) * rstd * 0.015625f;
    }

    // ---- pass 2: prefix-G sweep; emit output rows in order ----
    float G[64];
#pragma unroll
    for (int c = 0; c < 64; ++c) G[c] = 0.f;
    float g0 = 0.f;
#pragma unroll
    for (int i = 0; i < 16; ++i) {
      float ai = lane_bcast(lrl, i) * gr[i];
      g0 += ai;
#pragma unroll
      for (int c = 0; c < 64; ++c) G[c] += lane_bcast(kr[i], c) * ai;
      float xqw = 0.f, cor = 0.f;
#pragma unroll
      for (int c = 0; c < 64; ++c) {
        float qb = lane_bcast(qr[i], c);
        xqw += qb * Wr[c];
        cor += qb * G[c];
      }
      float zb = xqw + breg - tokr[i] * (cor + g0);
      float s1 = zb, s2 = zb * zb;
#pragma unroll
      for (int o = 1; o < 64; o <<= 1) { s1 += __shfl_xor(s1, o); s2 += __shfl_xor(s2, o); }
      float mu = s1 * 0.015625f;
      float var = s2 * 0.015625f - mu * mu;
      float rstd = rsqrtf(var + 1e-6f);
      float outv = qr[i] + gvr * (zb - mu) * rstd + btr;
      Zout[((size_t)b * Nseq + n0 + i) * W2D + h * 64 + l] = outv;
    }

    // ---- step-final W / b update (free via G_15, g0_15) ----
    float t15 = tokr[15];
#pragma unroll
    for (int c = 0; c < 64; ++c) Wr[c] -= t15 * G[c];
    breg -= t15 * g0;
  }
}

// ---------------- post-LN over W2=1536 ---------------------------------------
__global__ __launch_bounds__(256) void postln_kernel(
    const float* __restrict__ Z, const float* __restrict__ wv,
    const float* __restrict__ bb, float* __restrict__ out)
{
  __shared__ float red[8];
  const int row = blockIdx.x;
  const int t = threadIdx.x;
  const float* zr = Z + (size_t)row * W2D;
  float vals[6];
  float s1 = 0.f, s2 = 0.f;
#pragma unroll
  for (int r = 0; r < 6; ++r) { float v = zr[t + 256 * r]; vals[r] = v; s1 += v; s2 += v * v; }
#pragma unroll
  for (int o = 1; o < 64; o <<= 1) { s1 += __shfl_xor(s1, o); s2 += __shfl_xor(s2, o); }
  if ((t & 63) == 0) { red[t >> 6] = s1; red[4 + (t >> 6)] = s2; }
  __syncthreads();
  s1 = red[0] + red[1] + red[2] + red[3];
  s2 = red[4] + red[5] + red[6] + red[7];
  float mu = s1 * (1.f / 1536.f);
  float var = s2 * (1.f / 1536.f) - mu * mu;
  float rstd = rsqrtf(var + 1e-6f);
  float* orow = out + (size_t)row * W2D;
#pragma unroll
  for (int r = 0; r < 6; ++r) {
    int c = t + 256 * r;
    orow[c] = wv[c] * (vals[r] - mu) * rstd + bb[c];
  }
}

// ---------------- h[b,n,c] = Zln[b,n,c] * Zln[b,N-1-n,768+c] -----------------
__global__ __launch_bounds__(256) void mult_kernel(
    const float* __restrict__ Zln, float* __restrict__ hbuf)
{
  int idx = blockIdx.x * 256 + threadIdx.x;
  int c = idx % Cdim;
  int row = idx / Cdim;     // b*N + n
  int b = row >> 10, n = row & 1023;
  float zf = Zln[(size_t)row * W2D + c];
  float zb = Zln[(size_t)(b * Nseq + (Nseq - 1 - n)) * W2D + Cdim + c];
  hbuf[idx] = zf * zb;
}

// ---------------- launch -----------------------------------------------------
extern "C" void kernel_launch(void* const* d_in, const int* in_sizes, int n_in,
                              void* d_out, int out_size, void* d_ws, size_t ws_size,
                              hipStream_t stream)
{
  const float* x         = (const float*)d_in[0];
  const float* qkv_w     = (const float*)d_in[1];
  const float* proj_w    = (const float*)d_in[2];
  const float* proj_b    = (const float*)d_in[3];
  const float* W1        = (const float*)d_in[4];
  const float* b1        = (const float*)d_in[5];
  const float* ttt_ln_w  = (const float*)d_in[6];
  const float* ttt_ln_b  = (const float*)d_in[7];
  const float* post_ln_w = (const float*)d_in[8];
  const float* post_ln_b = (const float*)d_in[9];
  const float* lr_w      = (const float*)d_in[10];
  const float* lr_b      = (const float*)d_in[11];
  const float* tid       = (const float*)d_in[12];
  float* out = (float*)d_out;
  float* ws  = (float*)d_ws;

  // workspace layout (floats)
  float* qkv   = ws;                       // 16384*2304 = 37,748,736
  float* lrbuf = ws + 37748736;            // 393,216
  float* Zbuf  = ws + 38141952;            // 25,165,824
  // after the scan, the qkv region is dead — reuse it:
  float* Zln   = ws;                       // 25,165,824
  float* hbuf  = ws + 25165824;            // 12,582,912

  const int Mrows = Bq * Nseq;             // 16384

  dim3 g1(3 * Cdim / 64, Mrows / 64);      // (36, 256)
  gemm_f32_kernel<<<g1, 256, 0, stream>>>(x, qkv_w, nullptr, qkv, Mrows, Cdim, 3 * Cdim);

  lr_kernel<<<(Mrows * NH2 + 255) / 256, 256, 0, stream>>>(x, lr_w, lr_b, lrbuf);

  ttt_scan_reg_kernel<<<Bq * NH2, 64, 0, stream>>>(qkv, lrbuf, W1, b1, ttt_ln_w, ttt_ln_b, tid, Zbuf);

  postln_kernel<<<Mrows, 256, 0, stream>>>(Zbuf, post_ln_w, post_ln_b, Zln);

  mult_kernel<<<(Mrows * Cdim) / 256, 256, 0, stream>>>(Zln, hbuf);

  dim3 g2(Cdim / 64, Mrows / 64);          // (12, 256)
  gemm_f32_kernel<<<g2, 256, 0, stream>>>(hbuf, proj_w, proj_b, out, Mrows, Cdim, Cdim);
}

// Round 3
// 2323.053 us; speedup vs baseline: 2.1065x; 2.1065x over previous
//
#include <hip/hip_runtime.h>
#include <hip/hip_bf16.h>

#define Bq   16
#define Nseq 1024
#define Cdim 768
#define NH2  24
#define W2D  1536
#define KB   16
#define NMB  64

typedef short bfrag8 __attribute__((ext_vector_type(8)));   // 8 bf16 (4 VGPRs)
typedef float f32x4  __attribute__((ext_vector_type(4)));

__device__ __forceinline__ short f2bs(float x) {
  union { __hip_bfloat16 b; short s; } u;
  u.b = __float2bfloat16(x);
  return u.s;
}
__device__ __forceinline__ bfrag8 cvt8(const float* v) {
  bfrag8 r;
#pragma unroll
  for (int i = 0; i < 8; ++i) r[i] = f2bs(v[i]);
  return r;
}

// ---------------- generic f32 tiled GEMM: C[M,N] = A[M,K] @ B[K,N] (+bias) ---
__global__ __launch_bounds__(256) void gemm_f32_kernel(
    const float* __restrict__ A, const float* __restrict__ B,
    const float* __restrict__ bias, float* __restrict__ C,
    int M, int Kd, int Nd)
{
  __shared__ float As[64 * 17];
  __shared__ float Bs[16 * 65];
  const int t = threadIdx.x;
  const int tx = t & 15, ty = t >> 4;
  const int bx = blockIdx.x * 64, by = blockIdx.y * 64;
  float acc[4][4] = {};
  for (int k0 = 0; k0 < Kd; k0 += 16) {
#pragma unroll
    for (int r = 0; r < 4; ++r) {
      int q = t + 256 * r;
      int m = q >> 4, kk = q & 15;
      As[m * 17 + kk] = A[(size_t)(by + m) * Kd + k0 + kk];
    }
#pragma unroll
    for (int r = 0; r < 4; ++r) {
      int q = t + 256 * r;
      int kk = q >> 6, n = q & 63;
      Bs[kk * 65 + n] = B[(size_t)(k0 + kk) * Nd + bx + n];
    }
    __syncthreads();
#pragma unroll
    for (int kk = 0; kk < 16; ++kk) {
      float av[4], bv[4];
#pragma unroll
      for (int i2 = 0; i2 < 4; ++i2) av[i2] = As[(ty * 4 + i2) * 17 + kk];
#pragma unroll
      for (int j2 = 0; j2 < 4; ++j2) bv[j2] = Bs[kk * 65 + tx * 4 + j2];
#pragma unroll
      for (int i2 = 0; i2 < 4; ++i2)
#pragma unroll
        for (int j2 = 0; j2 < 4; ++j2)
          acc[i2][j2] += av[i2] * bv[j2];
    }
    __syncthreads();
  }
#pragma unroll
  for (int i2 = 0; i2 < 4; ++i2) {
    int row = by + ty * 4 + i2;
#pragma unroll
    for (int j2 = 0; j2 < 4; ++j2) {
      int col = bx + tx * 4 + j2;
      float v = acc[i2][j2];
      if (bias) v += bias[col];
      C[(size_t)row * Nd + col] = v;
    }
  }
}

// ---------------- lr = sigmoid(xx @ lr_w + lr_b) / hd ------------------------
__global__ __launch_bounds__(256) void lr_kernel(
    const float* __restrict__ x, const float* __restrict__ lr_w,
    const float* __restrict__ lr_b, float* __restrict__ lrout)
{
  int idx = blockIdx.x * 256 + threadIdx.x;
  if (idx >= Bq * Nseq * NH2) return;
  int hh = idx % NH2;
  int row = idx / NH2;
  int b = row >> 10, n = row & 1023;
  const float* x1 = x + (size_t)row * Cdim;
  const float* x2 = x + (size_t)(b * Nseq + (Nseq - 1 - n)) * Cdim;
  float acc = lr_b[hh];
  for (int c = 0; c < Cdim; ++c) acc += x1[c] * lr_w[c * NH2 + hh];
  for (int c = 0; c < Cdim; ++c) acc += x2[c] * lr_w[(Cdim + c) * NH2 + hh];
  float sg = 1.f / (1.f + expf(-acc));
  lrout[idx] = sg * (1.f / 64.f);
}

// ---------------- MFMA TTT scan: ONE WAVE per (b,h) chain --------------------
// Frag layouts (mfma_f32_16x16x32_bf16, verified m89/m91/m120):
//   A[m=lane&15][k=quad*8+j]   B[n=lane&15][k=quad*8+j]
//   C/D: col=lane&15, row=quad*4+reg
// Algebra: gradS_j = lr_j*grad_j ; coef_ij = -tok_i*(attn_ij+1)*[j<=i]
//   Z1_bar = xq@W + b + coef@gradS ; W -= tok15 * xk^T@gradS ; b -= tok15*sum_j gradS_j
__global__ __launch_bounds__(64, 1) void ttt_scan_mfma_kernel(
    const float* __restrict__ qkv,   // (B,N,2304)
    const float* __restrict__ lrg,   // (B,N,24)
    const float* __restrict__ W1,    // (24,64,64) [ch_in][ch_out]
    const float* __restrict__ b1g,   // (24,64)
    const float* __restrict__ lnw,   // (24,64)
    const float* __restrict__ lnb,   // (24,64)
    const float* __restrict__ tid,   // (16,)
    float* __restrict__ Zout)        // (B,N,1536)
{
  __shared__ float sQ[16 * 68], sK[16 * 68], sV[16 * 68], sG[16 * 68];
  __shared__ float sC[16 * 17];
  __shared__ float sWG[64 * 67];

  const int l = threadIdx.x, quad = l >> 4, li = l & 15;
  const int bh = blockIdx.x, b = bh / NH2, h = bh % NH2;
  const int chan = (h < 12) ? h * 64 : (h - 12) * 64;
  const bool flip = (h >= 12);
  const int bN = b * Nseq;

  // W state in B-frag layout: Wf[t][c][j] = W[c*32+quad*8+j][t*16+li]
  float Wf[4][2][8];
  bfrag8 wB[4][2];
#pragma unroll
  for (int t = 0; t < 4; ++t)
#pragma unroll
    for (int c = 0; c < 2; ++c) {
#pragma unroll
      for (int j = 0; j < 8; ++j)
        Wf[t][c][j] = W1[h * 4096 + (c * 32 + quad * 8 + j) * 64 + t * 16 + li];
      wB[t][c] = cvt8(Wf[t][c]);
    }
  float bC[4], gvC[4], btC[4];
#pragma unroll
  for (int t = 0; t < 4; ++t) {
    bC[t]  = b1g[h * 64 + t * 16 + li];
    gvC[t] = lnw[h * 64 + t * 16 + li];
    btC[t] = lnb[h * 64 + t * 16 + li];
  }
  float tokC[4];
#pragma unroll
  for (int r = 0; r < 4; ++r) {
    int i = quad * 4 + r;
    float tk = 1.f / (float)(i + 1) + tid[i];
    tokC[r] = tk > 0.f ? tk : 0.f;
  }
  float t15 = 1.f / 16.f + tid[15];
  t15 = t15 > 0.f ? t15 : 0.f;

  // rotary tables for staging layout: lane holds token l>>2, chs (l&3)*16..+15
  float c8[8], s8[8];
  {
    int pos = l >> 2;
#pragma unroll
    for (int pl = 0; pl < 8; ++pl) {
      int p = (l & 3) * 8 + pl;
      float inv = __expf(-((float)(2 * p) * (1.f / 64.f)) * 9.210340371976184f);
      float a = (float)pos * inv;
      c8[pl] = cosf(a);
      s8[pl] = sinf(a);
    }
  }

#pragma unroll 1
  for (int m = 0; m < NMB; ++m) {
    const int n0 = m * KB;
    float lrv = lrg[(size_t)(bN + n0 + li) * NH2 + h];

    // ---- stage q,k,v tile to LDS (rotary applied in-register) ----
    {
      int tL = l >> 2, colb = (l & 3) * 16;
      int n = n0 + tL;
      int grow = flip ? (bN + Nseq - 1 - n) : (bN + n);
      const float* base = qkv + (size_t)grow * 2304 + chan + colb;
      float qv[16], kv[16], vv[16];
#pragma unroll
      for (int i = 0; i < 4; ++i) {
        *(float4*)(qv + 4 * i) = *(const float4*)(base + 4 * i);
        *(float4*)(kv + 4 * i) = *(const float4*)(base + 768 + 4 * i);
        *(float4*)(vv + 4 * i) = *(const float4*)(base + 1536 + 4 * i);
      }
#pragma unroll
      for (int pl = 0; pl < 8; ++pl) {
        float e = qv[2 * pl], o = qv[2 * pl + 1];
        qv[2 * pl]     = e * c8[pl] - o * s8[pl];
        qv[2 * pl + 1] = o * c8[pl] + e * s8[pl];
        e = kv[2 * pl]; o = kv[2 * pl + 1];
        kv[2 * pl]     = e * c8[pl] - o * s8[pl];
        kv[2 * pl + 1] = o * c8[pl] + e * s8[pl];
      }
#pragma unroll
      for (int i = 0; i < 4; ++i) {
        *(float4*)(&sQ[tL * 68 + colb + 4 * i]) = *(float4*)(qv + 4 * i);
        *(float4*)(&sK[tL * 68 + colb + 4 * i]) = *(float4*)(kv + 4 * i);
        *(float4*)(&sV[tL * 68 + colb + 4 * i]) = *(float4*)(vv + 4 * i);
      }
    }
    __syncthreads();

    // ---- fragments from LDS ----
    bfrag8 aQ[2], aK[2];
#pragma unroll
    for (int c = 0; c < 2; ++c) {
      float tmp[8];
      *(float4*)(tmp)     = *(const float4*)(&sQ[li * 68 + c * 32 + quad * 8]);
      *(float4*)(tmp + 4) = *(const float4*)(&sQ[li * 68 + c * 32 + quad * 8 + 4]);
      aQ[c] = cvt8(tmp);
      *(float4*)(tmp)     = *(const float4*)(&sK[li * 68 + c * 32 + quad * 8]);
      *(float4*)(tmp + 4) = *(const float4*)(&sK[li * 68 + c * 32 + quad * 8 + 4]);
      aK[c] = cvt8(tmp);
    }
    float kC[4][4], vC[4][4], qC[4][4];
#pragma unroll
    for (int t = 0; t < 4; ++t)
#pragma unroll
      for (int r = 0; r < 4; ++r) {
        int off = (quad * 4 + r) * 68 + t * 16 + li;
        kC[t][r] = sK[off]; vC[t][r] = sV[off]; qC[t][r] = sQ[off];
      }

    // ---- MFMA block 1: Z1 = xk@W, xqW = xq@W, attn = xq@xk^T ----
    f32x4 accZ[4], accQ[4], accA;
    accA = (f32x4){0.f, 0.f, 0.f, 0.f};
#pragma unroll
    for (int t = 0; t < 4; ++t) {
      accZ[t] = (f32x4){0.f, 0.f, 0.f, 0.f};
      accQ[t] = (f32x4){0.f, 0.f, 0.f, 0.f};
    }
#pragma unroll
    for (int c = 0; c < 2; ++c) {
      accA = __builtin_amdgcn_mfma_f32_16x16x32_bf16(aQ[c], aK[c], accA, 0, 0, 0);
#pragma unroll
      for (int t = 0; t < 4; ++t) {
        accZ[t] = __builtin_amdgcn_mfma_f32_16x16x32_bf16(aK[c], wB[t][c], accZ[t], 0, 0, 0);
        accQ[t] = __builtin_amdgcn_mfma_f32_16x16x32_bf16(aQ[c], wB[t][c], accQ[t], 0, 0, 0);
      }
    }

    // ---- LN-L2 backward -> gradS (=lr_j*grad_j) -> sG; coef -> sC ----
    float lrC[4];
#pragma unroll
    for (int r = 0; r < 4; ++r) lrC[r] = __shfl(lrv, quad * 4 + r);
    float g0[4] = {0.f, 0.f, 0.f, 0.f};
#pragma unroll
    for (int r = 0; r < 4; ++r) {
      float z[4], s1 = 0.f, s2 = 0.f;
#pragma unroll
      for (int t = 0; t < 4; ++t) {
        z[t] = accZ[t][r] + bC[t];
        s1 += z[t]; s2 += z[t] * z[t];
      }
#pragma unroll
      for (int o = 1; o < 16; o <<= 1) { s1 += __shfl_xor(s1, o); s2 += __shfl_xor(s2, o); }
      float mu = s1 * 0.015625f;
      float var = s2 * 0.015625f - mu * mu;
      float rstd = rsqrtf(var + 1e-6f);
      float xh[4], gxh[4], r1 = 0.f, r2 = 0.f;
#pragma unroll
      for (int t = 0; t < 4; ++t) {
        xh[t] = (z[t] - mu) * rstd;
        float gout = gvC[t] * xh[t] + btC[t] - (vC[t][r] - kC[t][r]);
        gxh[t] = gout * gvC[t];
        r1 += gxh[t]; r2 += gxh[t] * xh[t];
      }
#pragma unroll
      for (int o = 1; o < 16; o <<= 1) { r1 += __shfl_xor(r1, o); r2 += __shfl_xor(r2, o); }
#pragma unroll
      for (int t = 0; t < 4; ++t) {
        float gd = (64.f * gxh[t] - r1 - xh[t] * r2) * rstd * 0.015625f;
        float gs = lrC[r] * gd;
        g0[t] += gs;
        sG[(quad * 4 + r) * 68 + t * 16 + li] = gs;
      }
      // coef row i = quad*4+r (C-layout: col j = li)
      int i = quad * 4 + r;
      float cf = (li <= i) ? (-tokC[r] * (accA[r] + 1.f)) : 0.f;
      sC[i * 17 + li] = cf;
    }
    __syncthreads();

    // ---- B-frag of gradS, A-frag of coef (K padded: quads 2,3 zero) ----
    bfrag8 bGrad[4], aCoef;
    {
      float tmp[8];
#pragma unroll
      for (int t = 0; t < 4; ++t) {
#pragma unroll
        for (int j = 0; j < 8; ++j)
          tmp[j] = (quad < 2) ? sG[(quad * 8 + j) * 68 + t * 16 + li] : 0.f;
        bGrad[t] = cvt8(tmp);
      }
#pragma unroll
      for (int j = 0; j < 8; ++j)
        tmp[j] = (quad < 2) ? sC[li * 17 + quad * 8 + j] : 0.f;
      aCoef = cvt8(tmp);
    }

    // ---- Z1_bar = xqW + b + coef@gradS ; LN ; output ----
#pragma unroll
    for (int t = 0; t < 4; ++t) {
      f32x4 acc = accQ[t];
#pragma unroll
      for (int r = 0; r < 4; ++r) acc[r] += bC[t];
      accQ[t] = __builtin_amdgcn_mfma_f32_16x16x32_bf16(aCoef, bGrad[t], acc, 0, 0, 0);
    }
#pragma unroll
    for (int r = 0; r < 4; ++r) {
      float zb[4], s1 = 0.f, s2 = 0.f;
#pragma unroll
      for (int t = 0; t < 4; ++t) {
        zb[t] = accQ[t][r];
        s1 += zb[t]; s2 += zb[t] * zb[t];
      }
#pragma unroll
      for (int o = 1; o < 16; o <<= 1) { s1 += __shfl_xor(s1, o); s2 += __shfl_xor(s2, o); }
      float mu = s1 * 0.015625f;
      float var = s2 * 0.015625f - mu * mu;
      float rstd = rsqrtf(var + 1e-6f);
      size_t row = (size_t)(bN + n0 + quad * 4 + r);
#pragma unroll
      for (int t = 0; t < 4; ++t) {
        float outv = qC[t][r] + gvC[t] * (zb[t] - mu) * rstd + btC[t];
        Zout[row * W2D + h * 64 + t * 16 + li] = outv;
      }
    }

    // ---- G = xk^T @ gradS (16 MFMAs) -> sWG -> W/b update ----
    bfrag8 aXkT[4];
    {
      float tmp[8];
#pragma unroll
      for (int mt = 0; mt < 4; ++mt) {
#pragma unroll
        for (int j = 0; j < 8; ++j)
          tmp[j] = (quad < 2) ? sK[(quad * 8 + j) * 68 + mt * 16 + li] : 0.f;
        aXkT[mt] = cvt8(tmp);
      }
    }
#pragma unroll
    for (int mt = 0; mt < 4; ++mt)
#pragma unroll
      for (int nt = 0; nt < 4; ++nt) {
        f32x4 g = (f32x4){0.f, 0.f, 0.f, 0.f};
        g = __builtin_amdgcn_mfma_f32_16x16x32_bf16(aXkT[mt], bGrad[nt], g, 0, 0, 0);
#pragma unroll
        for (int r = 0; r < 4; ++r)
          sWG[(mt * 16 + quad * 4 + r) * 67 + nt * 16 + li] = g[r];
      }
    __syncthreads();
#pragma unroll
    for (int t = 0; t < 4; ++t)
#pragma unroll
      for (int c = 0; c < 2; ++c) {
#pragma unroll
        for (int j = 0; j < 8; ++j)
          Wf[t][c][j] -= t15 * sWG[(c * 32 + quad * 8 + j) * 67 + t * 16 + li];
        wB[t][c] = cvt8(Wf[t][c]);
      }
#pragma unroll
    for (int t = 0; t < 4; ++t) {
      float v = g0[t];
      v += __shfl_xor(v, 16);
      v += __shfl_xor(v, 32);
      bC[t] -= t15 * v;
    }
    __syncthreads();
  }
}

// ---------------- post-LN over W2=1536 ---------------------------------------
__global__ __launch_bounds__(256) void postln_kernel(
    const float* __restrict__ Z, const float* __restrict__ wv,
    const float* __restrict__ bb, float* __restrict__ out)
{
  __shared__ float red[8];
  const int row = blockIdx.x;
  const int t = threadIdx.x;
  const float* zr = Z + (size_t)row * W2D;
  float vals[6];
  float s1 = 0.f, s2 = 0.f;
#pragma unroll
  for (int r = 0; r < 6; ++r) { float v = zr[t + 256 * r]; vals[r] = v; s1 += v; s2 += v * v; }
#pragma unroll
  for (int o = 1; o < 64; o <<= 1) { s1 += __shfl_xor(s1, o); s2 += __shfl_xor(s2, o); }
  if ((t & 63) == 0) { red[t >> 6] = s1; red[4 + (t >> 6)] = s2; }
  __syncthreads();
  s1 = red[0] + red[1] + red[2] + red[3];
  s2 = red[4] + red[5] + red[6] + red[7];
  float mu = s1 * (1.f / 1536.f);
  float var = s2 * (1.f / 1536.f) - mu * mu;
  float rstd = rsqrtf(var + 1e-6f);
  float* orow = out + (size_t)row * W2D;
#pragma unroll
  for (int r = 0; r < 6; ++r) {
    int c = t + 256 * r;
    orow[c] = wv[c] * (vals[r] - mu) * rstd + bb[c];
  }
}

// ---------------- h[b,n,c] = Zln[b,n,c] * Zln[b,N-1-n,768+c] -----------------
__global__ __launch_bounds__(256) void mult_kernel(
    const float* __restrict__ Zln, float* __restrict__ hbuf)
{
  int idx = blockIdx.x * 256 + threadIdx.x;
  int c = idx % Cdim;
  int row = idx / Cdim;
  int b = row >> 10, n = row & 1023;
  float zf = Zln[(size_t)row * W2D + c];
  float zb = Zln[(size_t)(b * Nseq + (Nseq - 1 - n)) * W2D + Cdim + c];
  hbuf[idx] = zf * zb;
}

// ---------------- launch -----------------------------------------------------
extern "C" void kernel_launch(void* const* d_in, const int* in_sizes, int n_in,
                              void* d_out, int out_size, void* d_ws, size_t ws_size,
                              hipStream_t stream)
{
  const float* x         = (const float*)d_in[0];
  const float* qkv_w     = (const float*)d_in[1];
  const float* proj_w    = (const float*)d_in[2];
  const float* proj_b    = (const float*)d_in[3];
  const float* W1        = (const float*)d_in[4];
  const float* b1        = (const float*)d_in[5];
  const float* ttt_ln_w  = (const float*)d_in[6];
  const float* ttt_ln_b  = (const float*)d_in[7];
  const float* post_ln_w = (const float*)d_in[8];
  const float* post_ln_b = (const float*)d_in[9];
  const float* lr_w      = (const float*)d_in[10];
  const float* lr_b      = (const float*)d_in[11];
  const float* tid       = (const float*)d_in[12];
  float* out = (float*)d_out;
  float* ws  = (float*)d_ws;

  float* qkv   = ws;                       // 37,748,736 floats
  float* lrbuf = ws + 37748736;            // 393,216
  float* Zbuf  = ws + 38141952;            // 25,165,824
  float* Zln   = ws;                       // reuse qkv region post-scan
  float* hbuf  = ws + 25165824;

  const int Mrows = Bq * Nseq;             // 16384

  dim3 g1(3 * Cdim / 64, Mrows / 64);
  gemm_f32_kernel<<<g1, 256, 0, stream>>>(x, qkv_w, nullptr, qkv, Mrows, Cdim, 3 * Cdim);

  lr_kernel<<<(Mrows * NH2 + 255) / 256, 256, 0, stream>>>(x, lr_w, lr_b, lrbuf);

  ttt_scan_mfma_kernel<<<Bq * NH2, 64, 0, stream>>>(qkv, lrbuf, W1, b1, ttt_ln_w, ttt_ln_b, tid, Zbuf);

  postln_kernel<<<Mrows, 256, 0, stream>>>(Zbuf, post_ln_w, post_ln_b, Zln);

  mult_kernel<<<(Mrows * Cdim) / 256, 256, 0, stream>>>(Zln, hbuf);

  dim3 g2(Cdim / 64, Mrows / 64);
  gemm_f32_kernel<<<g2, 256, 0, stream>>>(hbuf, proj_w, proj_b, out, Mrows, Cdim, Cdim);
}

// Round 4
// 1010.208 us; speedup vs baseline: 4.8440x; 2.2996x over previous
//
#include <hip/hip_runtime.h>
#include <hip/hip_bf16.h>

#define Bq   16
#define Nseq 1024
#define Cdim 768
#define NH2  24
#define W2D  1536
#define KB   16
#define NMB  64

typedef short bfrag8 __attribute__((ext_vector_type(8)));   // 8 bf16 (4 VGPRs)
typedef float f32x4  __attribute__((ext_vector_type(4)));

__device__ __forceinline__ short f2bs(float x) {
  union { __hip_bfloat16 b; short s; } u;
  u.b = __float2bfloat16(x);
  return u.s;
}
__device__ __forceinline__ bfrag8 cvt8(const float* v) {
  bfrag8 r;
#pragma unroll
  for (int i = 0; i < 8; ++i) r[i] = f2bs(v[i]);
  return r;
}
__device__ __forceinline__ void async_copy16(const void* g, void* l) {
  __builtin_amdgcn_global_load_lds((const __attribute__((address_space(1))) void*)g,
                                   (__attribute__((address_space(3))) void*)l, 16, 0, 0);
}

// ---------------- bf16 MFMA GEMM: C[M,N] = A[M,K] @ Bt[N,K]^T (+bias) --------
// 128x128 tile, BK=64, global_load_lds staging, XOR-swizzled LDS.
__global__ __launch_bounds__(256) void gemm_bf16_kernel(
    const __hip_bfloat16* __restrict__ A,   // M x K row-major
    const __hip_bfloat16* __restrict__ Bt,  // N x K row-major (B transposed)
    const float* __restrict__ bias, float* __restrict__ C,
    int M, int Kd, int Nd)
{
  __shared__ short sA[128 * 64];
  __shared__ short sB[128 * 64];
  const int t = threadIdx.x;
  const int w = t >> 6, lane = t & 63;
  const int quad = lane >> 4, li = lane & 15;
  const int wm = w & 1, wn = w >> 1;
  const int m0 = blockIdx.y * 128, n0 = blockIdx.x * 128;

  f32x4 acc[4][4];
#pragma unroll
  for (int mt = 0; mt < 4; ++mt)
#pragma unroll
    for (int nt = 0; nt < 4; ++nt) acc[mt][nt] = (f32x4){0.f, 0.f, 0.f, 0.f};

  const __hip_bfloat16* Ab = A + (size_t)m0 * Kd;
  const __hip_bfloat16* Bb = Bt + (size_t)n0 * Kd;

#pragma unroll 1
  for (int k0 = 0; k0 < Kd; k0 += 64) {
    __syncthreads();   // prev iter's LDS reads done before overwrite
#pragma unroll
    for (int i = 0; i < 4; ++i) {
      int c = i * 256 + t;
      int row = c >> 3;
      int gl = (c & 7) ^ (row & 7);            // XOR swizzle (16B granules)
      async_copy16(Ab + (size_t)row * Kd + k0 + gl * 8, &sA[c * 8]);
      async_copy16(Bb + (size_t)row * Kd + k0 + gl * 8, &sB[c * 8]);
    }
    __syncthreads();   // compiler drains vmcnt(0) before barrier -> LDS ready
#pragma unroll
    for (int ks = 0; ks < 2; ++ks) {
      bfrag8 aF[4], bF[4];
#pragma unroll
      for (int mt = 0; mt < 4; ++mt) {
        int row = wm * 64 + mt * 16 + li;
        int gi = (ks * 4 + quad) ^ (row & 7);
        aF[mt] = *(const bfrag8*)(&sA[row * 64 + gi * 8]);
      }
#pragma unroll
      for (int nt = 0; nt < 4; ++nt) {
        int row = wn * 64 + nt * 16 + li;
        int gi = (ks * 4 + quad) ^ (row & 7);
        bF[nt] = *(const bfrag8*)(&sB[row * 64 + gi * 8]);
      }
#pragma unroll
      for (int mt = 0; mt < 4; ++mt)
#pragma unroll
        for (int nt = 0; nt < 4; ++nt)
          acc[mt][nt] = __builtin_amdgcn_mfma_f32_16x16x32_bf16(aF[mt], bF[nt], acc[mt][nt], 0, 0, 0);
    }
  }

#pragma unroll
  for (int mt = 0; mt < 4; ++mt)
#pragma unroll
    for (int nt = 0; nt < 4; ++nt) {
      int ncol = n0 + wn * 64 + nt * 16 + li;
      float bv = bias ? bias[ncol] : 0.f;
#pragma unroll
      for (int r = 0; r < 4; ++r) {
        int mrow = m0 + wm * 64 + mt * 16 + quad * 4 + r;
        C[(size_t)mrow * Nd + ncol] = acc[mt][nt][r] + bv;
      }
    }
}

// ---------------- f32 -> bf16 cast (x4 vectorized) ---------------------------
__global__ __launch_bounds__(256) void cast_bf16_kernel(
    const float* __restrict__ in, __hip_bfloat16* __restrict__ out, int n4)
{
  int i = blockIdx.x * 256 + threadIdx.x;
  if (i >= n4) return;
  float4 v = ((const float4*)in)[i];
  union { short b[4]; short4 s; } u;
  u.b[0] = f2bs(v.x); u.b[1] = f2bs(v.y); u.b[2] = f2bs(v.z); u.b[3] = f2bs(v.w);
  ((short4*)out)[i] = u.s;
}

// ---------------- transpose + cast: Bt[n][k] = (bf16)B[k][n] -----------------
__global__ __launch_bounds__(256) void transpose_cast_kernel(
    const float* __restrict__ B, __hip_bfloat16* __restrict__ Bt, int Kd, int Nd)
{
  __shared__ float tl[64][65];
  int k0 = blockIdx.x * 64, n0 = blockIdx.y * 64;
  int tx = threadIdx.x & 63, ty = threadIdx.x >> 6;
#pragma unroll
  for (int i = 0; i < 16; ++i) {
    int k = ty + i * 4;
    tl[k][tx] = B[(size_t)(k0 + k) * Nd + n0 + tx];
  }
  __syncthreads();
#pragma unroll
  for (int i = 0; i < 16; ++i) {
    int n = ty + i * 4;
    Bt[(size_t)(n0 + n) * Kd + k0 + tx] = __float2bfloat16(tl[tx][n]);
  }
}

// ---------------- lr = sigmoid(xx @ lr_w + lr_b) / hd ------------------------
__global__ __launch_bounds__(256) void lr_kernel(
    const float* __restrict__ x, const float* __restrict__ lr_w,
    const float* __restrict__ lr_b, float* __restrict__ lrout)
{
  int idx = blockIdx.x * 256 + threadIdx.x;
  if (idx >= Bq * Nseq * NH2) return;
  int hh = idx % NH2;
  int row = idx / NH2;
  int b = row >> 10, n = row & 1023;
  const float* x1 = x + (size_t)row * Cdim;
  const float* x2 = x + (size_t)(b * Nseq + (Nseq - 1 - n)) * Cdim;
  float acc = lr_b[hh];
  for (int c = 0; c < Cdim; ++c) acc += x1[c] * lr_w[c * NH2 + hh];
  for (int c = 0; c < Cdim; ++c) acc += x2[c] * lr_w[(Cdim + c) * NH2 + hh];
  float sg = 1.f / (1.f + expf(-acc));
  lrout[idx] = sg * (1.f / 64.f);
}

// ---------------- MFMA TTT scan: ONE WAVE per (b,h) chain --------------------
__global__ __launch_bounds__(64, 1) void ttt_scan_mfma_kernel(
    const float* __restrict__ qkv,   // (B,N,2304)
    const float* __restrict__ lrg,   // (B,N,24)
    const float* __restrict__ W1,    // (24,64,64) [ch_in][ch_out]
    const float* __restrict__ b1g,   // (24,64)
    const float* __restrict__ lnw,   // (24,64)
    const float* __restrict__ lnb,   // (24,64)
    const float* __restrict__ tid,   // (16,)
    float* __restrict__ Zout)        // (B,N,1536)
{
  __shared__ float sQ[16 * 68], sK[16 * 68], sV[16 * 68], sG[16 * 68];
  __shared__ float sC[16 * 17];
  __shared__ float sWG[64 * 67];

  const int l = threadIdx.x, quad = l >> 4, li = l & 15;
  const int bh = blockIdx.x, b = bh / NH2, h = bh % NH2;
  const int chan = (h < 12) ? h * 64 : (h - 12) * 64;
  const bool flip = (h >= 12);
  const int bN = b * Nseq;

  float Wf[4][2][8];
  bfrag8 wB[4][2];
#pragma unroll
  for (int t = 0; t < 4; ++t)
#pragma unroll
    for (int c = 0; c < 2; ++c) {
#pragma unroll
      for (int j = 0; j < 8; ++j)
        Wf[t][c][j] = W1[h * 4096 + (c * 32 + quad * 8 + j) * 64 + t * 16 + li];
      wB[t][c] = cvt8(Wf[t][c]);
    }
  float bC[4], gvC[4], btC[4];
#pragma unroll
  for (int t = 0; t < 4; ++t) {
    bC[t]  = b1g[h * 64 + t * 16 + li];
    gvC[t] = lnw[h * 64 + t * 16 + li];
    btC[t] = lnb[h * 64 + t * 16 + li];
  }
  float tokC[4];
#pragma unroll
  for (int r = 0; r < 4; ++r) {
    int i = quad * 4 + r;
    float tk = 1.f / (float)(i + 1) + tid[i];
    tokC[r] = tk > 0.f ? tk : 0.f;
  }
  float t15 = 1.f / 16.f + tid[15];
  t15 = t15 > 0.f ? t15 : 0.f;

  float c8[8], s8[8];
  {
    int pos = l >> 2;
#pragma unroll
    for (int pl = 0; pl < 8; ++pl) {
      int p = (l & 3) * 8 + pl;
      float inv = __expf(-((float)(2 * p) * (1.f / 64.f)) * 9.210340371976184f);
      float a = (float)pos * inv;
      c8[pl] = cosf(a);
      s8[pl] = sinf(a);
    }
  }

#pragma unroll 1
  for (int m = 0; m < NMB; ++m) {
    const int n0 = m * KB;
    float lrv = lrg[(size_t)(bN + n0 + li) * NH2 + h];

    {
      int tL = l >> 2, colb = (l & 3) * 16;
      int n = n0 + tL;
      int grow = flip ? (bN + Nseq - 1 - n) : (bN + n);
      const float* base = qkv + (size_t)grow * 2304 + chan + colb;
      float qv[16], kv[16], vv[16];
#pragma unroll
      for (int i = 0; i < 4; ++i) {
        *(float4*)(qv + 4 * i) = *(const float4*)(base + 4 * i);
        *(float4*)(kv + 4 * i) = *(const float4*)(base + 768 + 4 * i);
        *(float4*)(vv + 4 * i) = *(const float4*)(base + 1536 + 4 * i);
      }
#pragma unroll
      for (int pl = 0; pl < 8; ++pl) {
        float e = qv[2 * pl], o = qv[2 * pl + 1];
        qv[2 * pl]     = e * c8[pl] - o * s8[pl];
        qv[2 * pl + 1] = o * c8[pl] + e * s8[pl];
        e = kv[2 * pl]; o = kv[2 * pl + 1];
        kv[2 * pl]     = e * c8[pl] - o * s8[pl];
        kv[2 * pl + 1] = o * c8[pl] + e * s8[pl];
      }
#pragma unroll
      for (int i = 0; i < 4; ++i) {
        *(float4*)(&sQ[tL * 68 + colb + 4 * i]) = *(float4*)(qv + 4 * i);
        *(float4*)(&sK[tL * 68 + colb + 4 * i]) = *(float4*)(kv + 4 * i);
        *(float4*)(&sV[tL * 68 + colb + 4 * i]) = *(float4*)(vv + 4 * i);
      }
    }
    __syncthreads();

    bfrag8 aQ[2], aK[2];
#pragma unroll
    for (int c = 0; c < 2; ++c) {
      float tmp[8];
      *(float4*)(tmp)     = *(const float4*)(&sQ[li * 68 + c * 32 + quad * 8]);
      *(float4*)(tmp + 4) = *(const float4*)(&sQ[li * 68 + c * 32 + quad * 8 + 4]);
      aQ[c] = cvt8(tmp);
      *(float4*)(tmp)     = *(const float4*)(&sK[li * 68 + c * 32 + quad * 8]);
      *(float4*)(tmp + 4) = *(const float4*)(&sK[li * 68 + c * 32 + quad * 8 + 4]);
      aK[c] = cvt8(tmp);
    }
    float kC[4][4], vC[4][4], qC[4][4];
#pragma unroll
    for (int t = 0; t < 4; ++t)
#pragma unroll
      for (int r = 0; r < 4; ++r) {
        int off = (quad * 4 + r) * 68 + t * 16 + li;
        kC[t][r] = sK[off]; vC[t][r] = sV[off]; qC[t][r] = sQ[off];
      }

    f32x4 accZ[4], accQ[4], accA;
    accA = (f32x4){0.f, 0.f, 0.f, 0.f};
#pragma unroll
    for (int t = 0; t < 4; ++t) {
      accZ[t] = (f32x4){0.f, 0.f, 0.f, 0.f};
      accQ[t] = (f32x4){0.f, 0.f, 0.f, 0.f};
    }
#pragma unroll
    for (int c = 0; c < 2; ++c) {
      accA = __builtin_amdgcn_mfma_f32_16x16x32_bf16(aQ[c], aK[c], accA, 0, 0, 0);
#pragma unroll
      for (int t = 0; t < 4; ++t) {
        accZ[t] = __builtin_amdgcn_mfma_f32_16x16x32_bf16(aK[c], wB[t][c], accZ[t], 0, 0, 0);
        accQ[t] = __builtin_amdgcn_mfma_f32_16x16x32_bf16(aQ[c], wB[t][c], accQ[t], 0, 0, 0);
      }
    }

    float lrC[4];
#pragma unroll
    for (int r = 0; r < 4; ++r) lrC[r] = __shfl(lrv, quad * 4 + r);
    float g0[4] = {0.f, 0.f, 0.f, 0.f};
#pragma unroll
    for (int r = 0; r < 4; ++r) {
      float z[4], s1 = 0.f, s2 = 0.f;
#pragma unroll
      for (int t = 0; t < 4; ++t) {
        z[t] = accZ[t][r] + bC[t];
        s1 += z[t]; s2 += z[t] * z[t];
      }
#pragma unroll
      for (int o = 1; o < 16; o <<= 1) { s1 += __shfl_xor(s1, o); s2 += __shfl_xor(s2, o); }
      float mu = s1 * 0.015625f;
      float var = s2 * 0.015625f - mu * mu;
      float rstd = rsqrtf(var + 1e-6f);
      float xh[4], gxh[4], r1 = 0.f, r2 = 0.f;
#pragma unroll
      for (int t = 0; t < 4; ++t) {
        xh[t] = (z[t] - mu) * rstd;
        float gout = gvC[t] * xh[t] + btC[t] - (vC[t][r] - kC[t][r]);
        gxh[t] = gout * gvC[t];
        r1 += gxh[t]; r2 += gxh[t] * xh[t];
      }
#pragma unroll
      for (int o = 1; o < 16; o <<= 1) { r1 += __shfl_xor(r1, o); r2 += __shfl_xor(r2, o); }
#pragma unroll
      for (int t = 0; t < 4; ++t) {
        float gd = (64.f * gxh[t] - r1 - xh[t] * r2) * rstd * 0.015625f;
        float gs = lrC[r] * gd;
        g0[t] += gs;
        sG[(quad * 4 + r) * 68 + t * 16 + li] = gs;
      }
      int i = quad * 4 + r;
      float cf = (li <= i) ? (-tokC[r] * (accA[r] + 1.f)) : 0.f;
      sC[i * 17 + li] = cf;
    }
    __syncthreads();

    bfrag8 bGrad[4], aCoef;
    {
      float tmp[8];
#pragma unroll
      for (int t = 0; t < 4; ++t) {
#pragma unroll
        for (int j = 0; j < 8; ++j)
          tmp[j] = (quad < 2) ? sG[(quad * 8 + j) * 68 + t * 16 + li] : 0.f;
        bGrad[t] = cvt8(tmp);
      }
#pragma unroll
      for (int j = 0; j < 8; ++j)
        tmp[j] = (quad < 2) ? sC[li * 17 + quad * 8 + j] : 0.f;
      aCoef = cvt8(tmp);
    }

#pragma unroll
    for (int t = 0; t < 4; ++t) {
      f32x4 acc = accQ[t];
#pragma unroll
      for (int r = 0; r < 4; ++r) acc[r] += bC[t];
      accQ[t] = __builtin_amdgcn_mfma_f32_16x16x32_bf16(aCoef, bGrad[t], acc, 0, 0, 0);
    }
#pragma unroll
    for (int r = 0; r < 4; ++r) {
      float zb[4], s1 = 0.f, s2 = 0.f;
#pragma unroll
      for (int t = 0; t < 4; ++t) {
        zb[t] = accQ[t][r];
        s1 += zb[t]; s2 += zb[t] * zb[t];
      }
#pragma unroll
      for (int o = 1; o < 16; o <<= 1) { s1 += __shfl_xor(s1, o); s2 += __shfl_xor(s2, o); }
      float mu = s1 * 0.015625f;
      float var = s2 * 0.015625f - mu * mu;
      float rstd = rsqrtf(var + 1e-6f);
      size_t row = (size_t)(bN + n0 + quad * 4 + r);
#pragma unroll
      for (int t = 0; t < 4; ++t) {
        float outv = qC[t][r] + gvC[t] * (zb[t] - mu) * rstd + btC[t];
        Zout[row * W2D + h * 64 + t * 16 + li] = outv;
      }
    }

    bfrag8 aXkT[4];
    {
      float tmp[8];
#pragma unroll
      for (int mt = 0; mt < 4; ++mt) {
#pragma unroll
        for (int j = 0; j < 8; ++j)
          tmp[j] = (quad < 2) ? sK[(quad * 8 + j) * 68 + mt * 16 + li] : 0.f;
        aXkT[mt] = cvt8(tmp);
      }
    }
#pragma unroll
    for (int mt = 0; mt < 4; ++mt)
#pragma unroll
      for (int nt = 0; nt < 4; ++nt) {
        f32x4 g = (f32x4){0.f, 0.f, 0.f, 0.f};
        g = __builtin_amdgcn_mfma_f32_16x16x32_bf16(aXkT[mt], bGrad[nt], g, 0, 0, 0);
#pragma unroll
        for (int r = 0; r < 4; ++r)
          sWG[(mt * 16 + quad * 4 + r) * 67 + nt * 16 + li] = g[r];
      }
    __syncthreads();
#pragma unroll
    for (int t = 0; t < 4; ++t)
#pragma unroll
      for (int c = 0; c < 2; ++c) {
#pragma unroll
        for (int j = 0; j < 8; ++j)
          Wf[t][c][j] -= t15 * sWG[(c * 32 + quad * 8 + j) * 67 + t * 16 + li];
        wB[t][c] = cvt8(Wf[t][c]);
      }
#pragma unroll
    for (int t = 0; t < 4; ++t) {
      float v = g0[t];
      v += __shfl_xor(v, 16);
      v += __shfl_xor(v, 32);
      bC[t] -= t15 * v;
    }
    __syncthreads();
  }
}

// ---------------- post-LN over W2=1536 ---------------------------------------
__global__ __launch_bounds__(256) void postln_kernel(
    const float* __restrict__ Z, const float* __restrict__ wv,
    const float* __restrict__ bb, float* __restrict__ out)
{
  __shared__ float red[8];
  const int row = blockIdx.x;
  const int t = threadIdx.x;
  const float* zr = Z + (size_t)row * W2D;
  float vals[6];
  float s1 = 0.f, s2 = 0.f;
#pragma unroll
  for (int r = 0; r < 6; ++r) { float v = zr[t + 256 * r]; vals[r] = v; s1 += v; s2 += v * v; }
#pragma unroll
  for (int o = 1; o < 64; o <<= 1) { s1 += __shfl_xor(s1, o); s2 += __shfl_xor(s2, o); }
  if ((t & 63) == 0) { red[t >> 6] = s1; red[4 + (t >> 6)] = s2; }
  __syncthreads();
  s1 = red[0] + red[1] + red[2] + red[3];
  s2 = red[4] + red[5] + red[6] + red[7];
  float mu = s1 * (1.f / 1536.f);
  float var = s2 * (1.f / 1536.f) - mu * mu;
  float rstd = rsqrtf(var + 1e-6f);
  float* orow = out + (size_t)row * W2D;
#pragma unroll
  for (int r = 0; r < 6; ++r) {
    int c = t + 256 * r;
    orow[c] = wv[c] * (vals[r] - mu) * rstd + bb[c];
  }
}

// ---------------- h(bf16)[b,n,c] = Zln[b,n,c] * Zln[b,N-1-n,768+c] -----------
__global__ __launch_bounds__(256) void mult_bf16_kernel(
    const float* __restrict__ Zln, __hip_bfloat16* __restrict__ hbuf)
{
  int idx = blockIdx.x * 256 + threadIdx.x;   // group of 4 channels
  int c4 = (idx % (Cdim / 4)) * 4;
  int row = idx / (Cdim / 4);
  int b = row >> 10, n = row & 1023;
  float4 zf = *(const float4*)(&Zln[(size_t)row * W2D + c4]);
  float4 zb = *(const float4*)(&Zln[(size_t)(b * Nseq + (Nseq - 1 - n)) * W2D + Cdim + c4]);
  union { short b4[4]; short4 s; } u;
  u.b4[0] = f2bs(zf.x * zb.x); u.b4[1] = f2bs(zf.y * zb.y);
  u.b4[2] = f2bs(zf.z * zb.z); u.b4[3] = f2bs(zf.w * zb.w);
  *(short4*)(&hbuf[(size_t)row * Cdim + c4]) = u.s;
}

// ---------------- launch -----------------------------------------------------
extern "C" void kernel_launch(void* const* d_in, const int* in_sizes, int n_in,
                              void* d_out, int out_size, void* d_ws, size_t ws_size,
                              hipStream_t stream)
{
  const float* x         = (const float*)d_in[0];
  const float* qkv_w     = (const float*)d_in[1];
  const float* proj_w    = (const float*)d_in[2];
  const float* proj_b    = (const float*)d_in[3];
  const float* W1        = (const float*)d_in[4];
  const float* b1        = (const float*)d_in[5];
  const float* ttt_ln_w  = (const float*)d_in[6];
  const float* ttt_ln_b  = (const float*)d_in[7];
  const float* post_ln_w = (const float*)d_in[8];
  const float* post_ln_b = (const float*)d_in[9];
  const float* lr_w      = (const float*)d_in[10];
  const float* lr_b      = (const float*)d_in[11];
  const float* tid       = (const float*)d_in[12];
  float* out = (float*)d_out;
  float* ws  = (float*)d_ws;

  // workspace (float units), total footprint 63,307,776 floats (as before):
  float* qkv   = ws;                                   // [0, 37748736)
  float* lrbuf = ws + 37748736;                        // [.., 38141952)
  float* Zbuf  = ws + 38141952;                        // [.., 63307776)
  // pre-scan tenants of the Zbuf region (dead before scan writes it):
  __hip_bfloat16* xbf    = (__hip_bfloat16*)(ws + 38141952);   // 12.58M bf16
  __hip_bfloat16* wqkv_t = (__hip_bfloat16*)(ws + 44433408);   // 1.77M bf16
  // post-scan tenants:
  float* Zln             = ws;                                  // reuse qkv region
  __hip_bfloat16* hbf    = (__hip_bfloat16*)(ws + 25165824);    // in qkv region
  __hip_bfloat16* wproj_t= (__hip_bfloat16*)(ws + 38141952);    // Zbuf dead after postln

  const int Mrows = Bq * Nseq;             // 16384

  // 1) cast x -> bf16
  cast_bf16_kernel<<<(Mrows * Cdim / 4 + 255) / 256, 256, 0, stream>>>(x, xbf, Mrows * Cdim / 4);
  // 2) transpose+cast qkv_w -> (2304,768)
  {
    dim3 g(Cdim / 64, 3 * Cdim / 64);
    transpose_cast_kernel<<<g, 256, 0, stream>>>(qkv_w, wqkv_t, Cdim, 3 * Cdim);
  }
  // 3) qkv = x @ qkv_w  (bf16 MFMA)
  {
    dim3 g(3 * Cdim / 128, Mrows / 128);   // (18, 128)
    gemm_bf16_kernel<<<g, 256, 0, stream>>>(xbf, wqkv_t, nullptr, qkv, Mrows, Cdim, 3 * Cdim);
  }
  // 4) lr
  lr_kernel<<<(Mrows * NH2 + 255) / 256, 256, 0, stream>>>(x, lr_w, lr_b, lrbuf);
  // 5) scan
  ttt_scan_mfma_kernel<<<Bq * NH2, 64, 0, stream>>>(qkv, lrbuf, W1, b1, ttt_ln_w, ttt_ln_b, tid, Zbuf);
  // 6) post-LN
  postln_kernel<<<Mrows, 256, 0, stream>>>(Zbuf, post_ln_w, post_ln_b, Zln);
  // 7) transpose+cast proj_w (Zbuf now dead)
  {
    dim3 g(Cdim / 64, Cdim / 64);
    transpose_cast_kernel<<<g, 256, 0, stream>>>(proj_w, wproj_t, Cdim, Cdim);
  }
  // 8) h = zf * flip(zb)  (bf16 out)
  mult_bf16_kernel<<<(Mrows * Cdim / 4) / 256, 256, 0, stream>>>(Zln, hbf);
  // 9) out = h @ proj_w + proj_b  (bf16 MFMA)
  {
    dim3 g(Cdim / 128, Mrows / 128);       // (6, 128)
    gemm_bf16_kernel<<<g, 256, 0, stream>>>(hbf, wproj_t, proj_b, out, Mrows, Cdim, Cdim);
  }
}

// Round 5
// 752.373 us; speedup vs baseline: 6.5040x; 1.3427x over previous
//
#include <hip/hip_runtime.h>
#include <hip/hip_bf16.h>

#define Bq   16
#define Nseq 1024
#define Cdim 768
#define NH2  24
#define W2D  1536
#define KB   16
#define NMB  64

typedef short bfrag8 __attribute__((ext_vector_type(8)));   // 8 bf16 (4 VGPRs)
typedef float f32x4  __attribute__((ext_vector_type(4)));

__device__ __forceinline__ short f2bs(float x) {
  union { __hip_bfloat16 b; short s; } u;
  u.b = __float2bfloat16(x);
  return u.s;
}
__device__ __forceinline__ bfrag8 cvt8(const float* v) {
  bfrag8 r;
#pragma unroll
  for (int i = 0; i < 8; ++i) r[i] = f2bs(v[i]);
  return r;
}
__device__ __forceinline__ void async_copy16(const void* g, void* l) {
  __builtin_amdgcn_global_load_lds((const __attribute__((address_space(1))) void*)g,
                                   (__attribute__((address_space(3))) void*)l, 16, 0, 0);
}

// ---------------- bf16 MFMA GEMM: C[M,N] = A[M,K] @ Bt[N,K]^T (+bias) --------
__global__ __launch_bounds__(256) void gemm_bf16_kernel(
    const __hip_bfloat16* __restrict__ A,   // M x K row-major
    const __hip_bfloat16* __restrict__ Bt,  // N x K row-major (B transposed)
    const float* __restrict__ bias, float* __restrict__ C,
    int M, int Kd, int Nd)
{
  __shared__ short sA[128 * 64];
  __shared__ short sB[128 * 64];
  const int t = threadIdx.x;
  const int w = t >> 6, lane = t & 63;
  const int quad = lane >> 4, li = lane & 15;
  const int wm = w & 1, wn = w >> 1;
  const int m0 = blockIdx.y * 128, n0 = blockIdx.x * 128;

  f32x4 acc[4][4];
#pragma unroll
  for (int mt = 0; mt < 4; ++mt)
#pragma unroll
    for (int nt = 0; nt < 4; ++nt) acc[mt][nt] = (f32x4){0.f, 0.f, 0.f, 0.f};

  const __hip_bfloat16* Ab = A + (size_t)m0 * Kd;
  const __hip_bfloat16* Bb = Bt + (size_t)n0 * Kd;

#pragma unroll 1
  for (int k0 = 0; k0 < Kd; k0 += 64) {
    __syncthreads();
#pragma unroll
    for (int i = 0; i < 4; ++i) {
      int c = i * 256 + t;
      int row = c >> 3;
      int gl = (c & 7) ^ (row & 7);
      async_copy16(Ab + (size_t)row * Kd + k0 + gl * 8, &sA[c * 8]);
      async_copy16(Bb + (size_t)row * Kd + k0 + gl * 8, &sB[c * 8]);
    }
    __syncthreads();
#pragma unroll
    for (int ks = 0; ks < 2; ++ks) {
      bfrag8 aF[4], bF[4];
#pragma unroll
      for (int mt = 0; mt < 4; ++mt) {
        int row = wm * 64 + mt * 16 + li;
        int gi = (ks * 4 + quad) ^ (row & 7);
        aF[mt] = *(const bfrag8*)(&sA[row * 64 + gi * 8]);
      }
#pragma unroll
      for (int nt = 0; nt < 4; ++nt) {
        int row = wn * 64 + nt * 16 + li;
        int gi = (ks * 4 + quad) ^ (row & 7);
        bF[nt] = *(const bfrag8*)(&sB[row * 64 + gi * 8]);
      }
#pragma unroll
      for (int mt = 0; mt < 4; ++mt)
#pragma unroll
        for (int nt = 0; nt < 4; ++nt)
          acc[mt][nt] = __builtin_amdgcn_mfma_f32_16x16x32_bf16(aF[mt], bF[nt], acc[mt][nt], 0, 0, 0);
    }
  }

#pragma unroll
  for (int mt = 0; mt < 4; ++mt)
#pragma unroll
    for (int nt = 0; nt < 4; ++nt) {
      int ncol = n0 + wn * 64 + nt * 16 + li;
      float bv = bias ? bias[ncol] : 0.f;
#pragma unroll
      for (int r = 0; r < 4; ++r) {
        int mrow = m0 + wm * 64 + mt * 16 + quad * 4 + r;
        C[(size_t)mrow * Nd + ncol] = acc[mt][nt][r] + bv;
      }
    }
}

// ---------------- f32 -> bf16 cast (x4 vectorized) ---------------------------
__global__ __launch_bounds__(256) void cast_bf16_kernel(
    const float* __restrict__ in, __hip_bfloat16* __restrict__ out, int n4)
{
  int i = blockIdx.x * 256 + threadIdx.x;
  if (i >= n4) return;
  float4 v = ((const float4*)in)[i];
  union { short b[4]; short4 s; } u;
  u.b[0] = f2bs(v.x); u.b[1] = f2bs(v.y); u.b[2] = f2bs(v.z); u.b[3] = f2bs(v.w);
  ((short4*)out)[i] = u.s;
}

// ---------------- transpose + cast: Bt[n][k] = (bf16)B[k][n] -----------------
__global__ __launch_bounds__(256) void transpose_cast_kernel(
    const float* __restrict__ B, __hip_bfloat16* __restrict__ Bt, int Kd, int Nd)
{
  __shared__ float tl[64][65];
  int k0 = blockIdx.x * 64, n0 = blockIdx.y * 64;
  int tx = threadIdx.x & 63, ty = threadIdx.x >> 6;
#pragma unroll
  for (int i = 0; i < 16; ++i) {
    int k = ty + i * 4;
    tl[k][tx] = B[(size_t)(k0 + k) * Nd + n0 + tx];
  }
  __syncthreads();
#pragma unroll
  for (int i = 0; i < 16; ++i) {
    int n = ty + i * 4;
    Bt[(size_t)(n0 + n) * Kd + k0 + tx] = __float2bfloat16(tl[tx][n]);
  }
}

// ---------------- lr = sigmoid(xx @ lr_w + lr_b) / hd ------------------------
__global__ __launch_bounds__(256) void lr_kernel(
    const float* __restrict__ x, const float* __restrict__ lr_w,
    const float* __restrict__ lr_b, float* __restrict__ lrout)
{
  int idx = blockIdx.x * 256 + threadIdx.x;
  if (idx >= Bq * Nseq * NH2) return;
  int hh = idx % NH2;
  int row = idx / NH2;
  int b = row >> 10, n = row & 1023;
  const float* x1 = x + (size_t)row * Cdim;
  const float* x2 = x + (size_t)(b * Nseq + (Nseq - 1 - n)) * Cdim;
  float acc = lr_b[hh];
  for (int c = 0; c < Cdim; ++c) acc += x1[c] * lr_w[c * NH2 + hh];
  for (int c = 0; c < Cdim; ++c) acc += x2[c] * lr_w[(Cdim + c) * NH2 + hh];
  float sg = 1.f / (1.f + expf(-acc));
  lrout[idx] = sg * (1.f / 64.f);
}

// ---------------- 4-wave MFMA TTT scan: one BLOCK per (b,h) chain ------------
// wave ot = output-channel tile [ot*16, ot*16+16). lane: quad=l>>4, li=l&15.
// Frag layouts (mfma_f32_16x16x32_bf16): A[m=li][k=quad*8+j], B[n=li][k=quad*8+j],
// C/D: col=li, row=quad*4+reg.
__global__ __launch_bounds__(256) void ttt_scan4_kernel(
    const float* __restrict__ qkv,   // (B,N,2304)
    const float* __restrict__ lrg,   // (B,N,24)
    const float* __restrict__ W1,    // (24,64,64) [ch_in][ch_out]
    const float* __restrict__ b1g,   // (24,64)
    const float* __restrict__ lnw,   // (24,64)
    const float* __restrict__ lnb,   // (24,64)
    const float* __restrict__ tid,   // (16,)
    float* __restrict__ Zout)        // (B,N,1536)
{
  __shared__ float sQ[16 * 68], sK[16 * 68], sV[16 * 68];  // staged rotary'd tiles
  __shared__ float sKT[64 * 24];    // xk transposed [ch][tok]
  __shared__ float sGT[64 * 24];    // gradS transposed [ch][tok]
  __shared__ float sC[16 * 24];     // coef [i][j]
  __shared__ float sWT[64 * 68];    // G transposed [out_ch][in_ch]
  __shared__ float red_s1[64], red_s2[64], red_r1[64], red_r2[64], red_z1[64], red_z2[64];

  const int t = threadIdx.x;
  const int ot = t >> 6;                 // wave id = output tile
  const int l = t & 63, quad = l >> 4, li = l & 15;
  const int bh = blockIdx.x, b = bh / NH2, h = bh % NH2;
  const int chan = (h < 12) ? h * 64 : (h - 12) * 64;
  const bool flip = (h >= 12);
  const int bN = b * Nseq;
  const int och = ot * 16 + li;          // this lane's output channel

  // W state (B-frag layout): Wf2[c][j] = W[c*32+quad*8+j][och]
  float Wf2[2][8];
  bfrag8 wB2[2];
#pragma unroll
  for (int c = 0; c < 2; ++c) {
#pragma unroll
    for (int j = 0; j < 8; ++j)
      Wf2[c][j] = W1[h * 4096 + (c * 32 + quad * 8 + j) * 64 + och];
    wB2[c] = cvt8(Wf2[c]);
  }
  float bC  = b1g[h * 64 + och];
  float gvC = lnw[h * 64 + och];
  float btC = lnb[h * 64 + och];

  float tokC[4];
#pragma unroll
  for (int r = 0; r < 4; ++r) {
    int i = quad * 4 + r;
    float tk = 1.f / (float)(i + 1) + tid[i];
    tokC[r] = tk > 0.f ? tk : 0.f;
  }
  float t15 = 1.f / 16.f + tid[15];
  t15 = t15 > 0.f ? t15 : 0.f;

  // staging rotary tables: lane holds token l>>2, channels (l&3)*16..+15
  float c8[8], s8[8];
  {
    int pos = l >> 2;
#pragma unroll
    for (int pl = 0; pl < 8; ++pl) {
      int p = (l & 3) * 8 + pl;
      float inv = __expf(-((float)(2 * p) * (1.f / 64.f)) * 9.210340371976184f);
      float a = (float)pos * inv;
      c8[pl] = cosf(a);
      s8[pl] = sinf(a);
    }
  }

  // prefetch registers (waves 0..2 stage q/k/v resp.; all waves load lr)
  float4 pf0, pf1, pf2, pf3;
  float pflr;
  {
    int nn = l >> 2;
    int grow = flip ? (bN + Nseq - 1 - nn) : (bN + nn);
    const float* bse = qkv + (size_t)grow * 2304 + chan + ot * 768 + (l & 3) * 16;
    if (ot < 3) {
      pf0 = ((const float4*)bse)[0]; pf1 = ((const float4*)bse)[1];
      pf2 = ((const float4*)bse)[2]; pf3 = ((const float4*)bse)[3];
    }
    pflr = lrg[(size_t)(bN + li) * NH2 + h];
  }

#pragma unroll 1
  for (int m = 0; m < NMB; ++m) {
    const int n0 = m * KB;

    // ---- stage from prefetch regs (rotary on q,k) ----
    if (ot < 3) {
      float v16[16];
      *(float4*)(v16)      = pf0; *(float4*)(v16 + 4)  = pf1;
      *(float4*)(v16 + 8)  = pf2; *(float4*)(v16 + 12) = pf3;
      if (ot < 2) {
#pragma unroll
        for (int pl = 0; pl < 8; ++pl) {
          float e = v16[2 * pl], o = v16[2 * pl + 1];
          v16[2 * pl]     = e * c8[pl] - o * s8[pl];
          v16[2 * pl + 1] = o * c8[pl] + e * s8[pl];
        }
      }
      float* dst = (ot == 0 ? sQ : (ot == 1 ? sK : sV)) + (l >> 2) * 68 + (l & 3) * 16;
#pragma unroll
      for (int i = 0; i < 4; ++i) ((f32x4*)dst)[i] = *(f32x4*)(v16 + 4 * i);
    }
    float lrl = pflr;
    __syncthreads();                              // barrier A

    // ---- issue prefetch for m+1 ----
    if (m < NMB - 1) {
      int nn = (m + 1) * KB + (l >> 2);
      int grow = flip ? (bN + Nseq - 1 - nn) : (bN + nn);
      const float* bse = qkv + (size_t)grow * 2304 + chan + ot * 768 + (l & 3) * 16;
      if (ot < 3) {
        pf0 = ((const float4*)bse)[0]; pf1 = ((const float4*)bse)[1];
        pf2 = ((const float4*)bse)[2]; pf3 = ((const float4*)bse)[3];
      }
      pflr = lrg[(size_t)(bN + (m + 1) * KB + li) * NH2 + h];
    }

    // ---- frags + C-reads ----
    bfrag8 aQ[2], aK[2];
#pragma unroll
    for (int c = 0; c < 2; ++c) {
      float tq[8], tk8[8];
      *(f32x4*)(tq)      = *(const f32x4*)(&sQ[li * 68 + c * 32 + quad * 8]);
      *(f32x4*)(tq + 4)  = *(const f32x4*)(&sQ[li * 68 + c * 32 + quad * 8 + 4]);
      *(f32x4*)(tk8)     = *(const f32x4*)(&sK[li * 68 + c * 32 + quad * 8]);
      *(f32x4*)(tk8 + 4) = *(const f32x4*)(&sK[li * 68 + c * 32 + quad * 8 + 4]);
      aQ[c] = cvt8(tq);
      aK[c] = cvt8(tk8);
    }
    float kCv[4], vCv[4], qCv[4];
#pragma unroll
    for (int r = 0; r < 4; ++r) {
      int off = (quad * 4 + r) * 68 + och;
      kCv[r] = sK[off]; vCv[r] = sV[off]; qCv[r] = sQ[off];
    }
    // xk^T scratch: sKT[ch][tok], one b128 per lane
    *(f32x4*)(&sKT[och * 24 + quad * 4]) = (f32x4){kCv[0], kCv[1], kCv[2], kCv[3]};

    // ---- MFMA 1: Z1 tile, xqW tile, (wave0) attn ----
    f32x4 accZ = (f32x4){0.f, 0.f, 0.f, 0.f};
    f32x4 accQ = (f32x4){0.f, 0.f, 0.f, 0.f};
#pragma unroll
    for (int c = 0; c < 2; ++c) {
      accZ = __builtin_amdgcn_mfma_f32_16x16x32_bf16(aK[c], wB2[c], accZ, 0, 0, 0);
      accQ = __builtin_amdgcn_mfma_f32_16x16x32_bf16(aQ[c], wB2[c], accQ, 0, 0, 0);
    }
    if (ot == 0) {
      f32x4 accA = (f32x4){0.f, 0.f, 0.f, 0.f};
      accA = __builtin_amdgcn_mfma_f32_16x16x32_bf16(aQ[0], aK[0], accA, 0, 0, 0);
      accA = __builtin_amdgcn_mfma_f32_16x16x32_bf16(aQ[1], aK[1], accA, 0, 0, 0);
#pragma unroll
      for (int r = 0; r < 4; ++r) {
        int i = quad * 4 + r;
        sC[i * 24 + li] = (li <= i) ? (-tokC[r] * (accA[r] + 1.f)) : 0.f;
      }
    }

    // ---- LN-L2 backward: cross-wave reductions via b128 scratch ----
    float z[4];
#pragma unroll
    for (int r = 0; r < 4; ++r) {
      z[r] = accZ[r] + bC;
      float s1 = z[r], s2 = z[r] * z[r];
#pragma unroll
      for (int o = 1; o < 16; o <<= 1) { s1 += __shfl_xor(s1, o); s2 += __shfl_xor(s2, o); }
      if (li == 0) {
        red_s1[(quad * 4 + r) * 4 + ot] = s1;
        red_s2[(quad * 4 + r) * 4 + ot] = s2;
      }
    }
    __syncthreads();                              // barrier C

    float xh[4], gxh[4], rstd1[4];
#pragma unroll
    for (int r = 0; r < 4; ++r) {
      f32x4 a1 = *(const f32x4*)(&red_s1[(quad * 4 + r) * 4]);
      f32x4 a2 = *(const f32x4*)(&red_s2[(quad * 4 + r) * 4]);
      float S1 = a1[0] + a1[1] + a1[2] + a1[3];
      float S2 = a2[0] + a2[1] + a2[2] + a2[3];
      float mu = S1 * 0.015625f;
      float var = S2 * 0.015625f - mu * mu;
      rstd1[r] = rsqrtf(var + 1e-6f);
      xh[r] = (z[r] - mu) * rstd1[r];
      float gout = gvC * xh[r] + btC - (vCv[r] - kCv[r]);
      gxh[r] = gout * gvC;
      float r1 = gxh[r], r2 = gxh[r] * xh[r];
#pragma unroll
      for (int o = 1; o < 16; o <<= 1) { r1 += __shfl_xor(r1, o); r2 += __shfl_xor(r2, o); }
      if (li == 0) {
        red_r1[(quad * 4 + r) * 4 + ot] = r1;
        red_r2[(quad * 4 + r) * 4 + ot] = r2;
      }
    }
    __syncthreads();                              // barrier D (also sC/sKT ready)

    float gs[4], g0 = 0.f;
#pragma unroll
    for (int r = 0; r < 4; ++r) {
      f32x4 a1 = *(const f32x4*)(&red_r1[(quad * 4 + r) * 4]);
      f32x4 a2 = *(const f32x4*)(&red_r2[(quad * 4 + r) * 4]);
      float R1 = a1[0] + a1[1] + a1[2] + a1[3];
      float R2 = a2[0] + a2[1] + a2[2] + a2[3];
      float lrr = __shfl(lrl, quad * 4 + r);
      float gd = (64.f * gxh[r] - R1 - xh[r] * R2) * rstd1[r] * 0.015625f;
      gs[r] = lrr * gd;
      g0 += gs[r];
    }
    // gradS transposed scratch (wave-private rows): 1 b128 write
    *(f32x4*)(&sGT[och * 24 + quad * 4]) = (f32x4){gs[0], gs[1], gs[2], gs[3]};

    // ---- build small K=16 frags (quads 2,3 zero-padded) ----
    bfrag8 aCoef, bGrad, aXkT[4];
    {
      float tmp[8];
      if (quad < 2) {
        *(f32x4*)(tmp)     = *(const f32x4*)(&sC[li * 24 + quad * 8]);
        *(f32x4*)(tmp + 4) = *(const f32x4*)(&sC[li * 24 + quad * 8 + 4]);
      } else {
#pragma unroll
        for (int j = 0; j < 8; ++j) tmp[j] = 0.f;
      }
      aCoef = cvt8(tmp);
      if (quad < 2) {
        *(f32x4*)(tmp)     = *(const f32x4*)(&sGT[och * 24 + quad * 8]);
        *(f32x4*)(tmp + 4) = *(const f32x4*)(&sGT[och * 24 + quad * 8 + 4]);
      } else {
#pragma unroll
        for (int j = 0; j < 8; ++j) tmp[j] = 0.f;
      }
      bGrad = cvt8(tmp);
#pragma unroll
      for (int mt = 0; mt < 4; ++mt) {
        if (quad < 2) {
          *(f32x4*)(tmp)     = *(const f32x4*)(&sKT[(mt * 16 + li) * 24 + quad * 8]);
          *(f32x4*)(tmp + 4) = *(const f32x4*)(&sKT[(mt * 16 + li) * 24 + quad * 8 + 4]);
        } else {
#pragma unroll
          for (int j = 0; j < 8; ++j) tmp[j] = 0.f;
        }
        aXkT[mt] = cvt8(tmp);
      }
    }

    // ---- Z1_bar = xqW + b + coef@gradS ; start LN reduction ----
    f32x4 zb;
    {
      f32x4 acc = accQ;
#pragma unroll
      for (int r = 0; r < 4; ++r) acc[r] += bC;
      zb = __builtin_amdgcn_mfma_f32_16x16x32_bf16(aCoef, bGrad, acc, 0, 0, 0);
    }
#pragma unroll
    for (int r = 0; r < 4; ++r) {
      float s1 = zb[r], s2 = zb[r] * zb[r];
#pragma unroll
      for (int o = 1; o < 16; o <<= 1) { s1 += __shfl_xor(s1, o); s2 += __shfl_xor(s2, o); }
      if (li == 0) {
        red_z1[(quad * 4 + r) * 4 + ot] = s1;
        red_z2[(quad * 4 + r) * 4 + ot] = s2;
      }
    }

    // ---- G = xk^T @ gradS (this wave's 16 output cols) ----
    f32x4 gAcc[4];
#pragma unroll
    for (int mt = 0; mt < 4; ++mt) {
      gAcc[mt] = (f32x4){0.f, 0.f, 0.f, 0.f};
      gAcc[mt] = __builtin_amdgcn_mfma_f32_16x16x32_bf16(aXkT[mt], bGrad, gAcc[mt], 0, 0, 0);
      *(f32x4*)(&sWT[och * 68 + mt * 16 + quad * 4]) = gAcc[mt];
    }
    __syncthreads();                              // barrier E

    // ---- finish LN ; write output ----
#pragma unroll
    for (int r = 0; r < 4; ++r) {
      f32x4 a1 = *(const f32x4*)(&red_z1[(quad * 4 + r) * 4]);
      f32x4 a2 = *(const f32x4*)(&red_z2[(quad * 4 + r) * 4]);
      float S1 = a1[0] + a1[1] + a1[2] + a1[3];
      float S2 = a2[0] + a2[1] + a2[2] + a2[3];
      float mu = S1 * 0.015625f;
      float var = S2 * 0.015625f - mu * mu;
      float rstd = rsqrtf(var + 1e-6f);
      float outv = qCv[r] + gvC * (zb[r] - mu) * rstd + btC;
      Zout[(size_t)(bN + n0 + quad * 4 + r) * W2D + h * 64 + och] = outv;
    }

    // ---- W / b update (sWT rows are wave-private: no extra barrier) ----
#pragma unroll
    for (int c = 0; c < 2; ++c) {
      float w8[8];
      *(f32x4*)(w8)     = *(const f32x4*)(&sWT[och * 68 + c * 32 + quad * 8]);
      *(f32x4*)(w8 + 4) = *(const f32x4*)(&sWT[och * 68 + c * 32 + quad * 8 + 4]);
#pragma unroll
      for (int j = 0; j < 8; ++j) Wf2[c][j] -= t15 * w8[j];
      wB2[c] = cvt8(Wf2[c]);
    }
    g0 += __shfl_xor(g0, 16);
    g0 += __shfl_xor(g0, 32);
    bC -= t15 * g0;
  }
}

// ---------------- post-LN over W2=1536 ---------------------------------------
__global__ __launch_bounds__(256) void postln_kernel(
    const float* __restrict__ Z, const float* __restrict__ wv,
    const float* __restrict__ bb, float* __restrict__ out)
{
  __shared__ float red[8];
  const int row = blockIdx.x;
  const int t = threadIdx.x;
  const float* zr = Z + (size_t)row * W2D;
  float vals[6];
  float s1 = 0.f, s2 = 0.f;
#pragma unroll
  for (int r = 0; r < 6; ++r) { float v = zr[t + 256 * r]; vals[r] = v; s1 += v; s2 += v * v; }
#pragma unroll
  for (int o = 1; o < 64; o <<= 1) { s1 += __shfl_xor(s1, o); s2 += __shfl_xor(s2, o); }
  if ((t & 63) == 0) { red[t >> 6] = s1; red[4 + (t >> 6)] = s2; }
  __syncthreads();
  s1 = red[0] + red[1] + red[2] + red[3];
  s2 = red[4] + red[5] + red[6] + red[7];
  float mu = s1 * (1.f / 1536.f);
  float var = s2 * (1.f / 1536.f) - mu * mu;
  float rstd = rsqrtf(var + 1e-6f);
  float* orow = out + (size_t)row * W2D;
#pragma unroll
  for (int r = 0; r < 6; ++r) {
    int c = t + 256 * r;
    orow[c] = wv[c] * (vals[r] - mu) * rstd + bb[c];
  }
}

// ---------------- h(bf16)[b,n,c] = Zln[b,n,c] * Zln[b,N-1-n,768+c] -----------
__global__ __launch_bounds__(256) void mult_bf16_kernel(
    const float* __restrict__ Zln, __hip_bfloat16* __restrict__ hbuf)
{
  int idx = blockIdx.x * 256 + threadIdx.x;
  int c4 = (idx % (Cdim / 4)) * 4;
  int row = idx / (Cdim / 4);
  int b = row >> 10, n = row & 1023;
  float4 zf = *(const float4*)(&Zln[(size_t)row * W2D + c4]);
  float4 zb = *(const float4*)(&Zln[(size_t)(b * Nseq + (Nseq - 1 - n)) * W2D + Cdim + c4]);
  union { short b4[4]; short4 s; } u;
  u.b4[0] = f2bs(zf.x * zb.x); u.b4[1] = f2bs(zf.y * zb.y);
  u.b4[2] = f2bs(zf.z * zb.z); u.b4[3] = f2bs(zf.w * zb.w);
  *(short4*)(&hbuf[(size_t)row * Cdim + c4]) = u.s;
}

// ---------------- launch -----------------------------------------------------
extern "C" void kernel_launch(void* const* d_in, const int* in_sizes, int n_in,
                              void* d_out, int out_size, void* d_ws, size_t ws_size,
                              hipStream_t stream)
{
  const float* x         = (const float*)d_in[0];
  const float* qkv_w     = (const float*)d_in[1];
  const float* proj_w    = (const float*)d_in[2];
  const float* proj_b    = (const float*)d_in[3];
  const float* W1        = (const float*)d_in[4];
  const float* b1        = (const float*)d_in[5];
  const float* ttt_ln_w  = (const float*)d_in[6];
  const float* ttt_ln_b  = (const float*)d_in[7];
  const float* post_ln_w = (const float*)d_in[8];
  const float* post_ln_b = (const float*)d_in[9];
  const float* lr_w      = (const float*)d_in[10];
  const float* lr_b      = (const float*)d_in[11];
  const float* tid       = (const float*)d_in[12];
  float* out = (float*)d_out;
  float* ws  = (float*)d_ws;

  float* qkv   = ws;                                   // [0, 37748736)
  float* lrbuf = ws + 37748736;                        // [.., 38141952)
  float* Zbuf  = ws + 38141952;                        // [.., 63307776)
  __hip_bfloat16* xbf    = (__hip_bfloat16*)(ws + 38141952);
  __hip_bfloat16* wqkv_t = (__hip_bfloat16*)(ws + 44433408);
  float* Zln             = ws;
  __hip_bfloat16* hbf    = (__hip_bfloat16*)(ws + 25165824);
  __hip_bfloat16* wproj_t= (__hip_bfloat16*)(ws + 38141952);

  const int Mrows = Bq * Nseq;             // 16384

  cast_bf16_kernel<<<(Mrows * Cdim / 4 + 255) / 256, 256, 0, stream>>>(x, xbf, Mrows * Cdim / 4);
  {
    dim3 g(Cdim / 64, 3 * Cdim / 64);
    transpose_cast_kernel<<<g, 256, 0, stream>>>(qkv_w, wqkv_t, Cdim, 3 * Cdim);
  }
  {
    dim3 g(3 * Cdim / 128, Mrows / 128);
    gemm_bf16_kernel<<<g, 256, 0, stream>>>(xbf, wqkv_t, nullptr, qkv, Mrows, Cdim, 3 * Cdim);
  }
  lr_kernel<<<(Mrows * NH2 + 255) / 256, 256, 0, stream>>>(x, lr_w, lr_b, lrbuf);

  ttt_scan4_kernel<<<Bq * NH2, 256, 0, stream>>>(qkv, lrbuf, W1, b1, ttt_ln_w, ttt_ln_b, tid, Zbuf);

  postln_kernel<<<Mrows, 256, 0, stream>>>(Zbuf, post_ln_w, post_ln_b, Zln);
  {
    dim3 g(Cdim / 64, Cdim / 64);
    transpose_cast_kernel<<<g, 256, 0, stream>>>(proj_w, wproj_t, Cdim, Cdim);
  }
  mult_bf16_kernel<<<(Mrows * Cdim / 4) / 256, 256, 0, stream>>>(Zln, hbf);
  {
    dim3 g(Cdim / 128, Mrows / 128);
    gemm_bf16_kernel<<<g, 256, 0, stream>>>(hbf, wproj_t, proj_b, out, Mrows, Cdim, Cdim);
  }
}